// Round 6
// baseline (440.725 us; speedup 1.0000x reference)
//
#include <hip/hip_runtime.h>
#include <math.h>

typedef short v8s __attribute__((ext_vector_type(8)));
typedef short v4s __attribute__((ext_vector_type(4)));
typedef float v4f __attribute__((ext_vector_type(4)));

__device__ __forceinline__ float b2f(unsigned short u) {
    return __uint_as_float(((unsigned)u) << 16);
}
__device__ __forceinline__ unsigned short f2b(float f) {
    unsigned u = __float_as_uint(f);
    unsigned r = (u + 0x7FFF + ((u >> 16) & 1)) >> 16;
    return (unsigned short)r;
}
__device__ __forceinline__ int swz8(int row) { return (row & 7) ^ ((row >> 3) & 7); }

// async global->LDS, 16B per lane; lds dest is wave-uniform base + lane*16
__device__ __forceinline__ void gl_lds16(const unsigned short* g, unsigned short* l) {
    __builtin_amdgcn_global_load_lds(
        (const __attribute__((address_space(1))) void*)g,
        (__attribute__((address_space(3))) void*)l,
        16, 0, 0);
}

// ---------------- prep: wT1 + wT2 transposes + zero_fill, one kernel ----------------
__global__ __launch_bounds__(256) void prep(const float* __restrict__ qkv_w,
                                            const float* __restrict__ out_w,
                                            unsigned short* __restrict__ wT1,
                                            unsigned short* __restrict__ wT2,
                                            float* __restrict__ zf) {
    __shared__ unsigned short tile[32][33];
    int bid = blockIdx.x;
    int t = threadIdx.x;
    if (bid >= 1024) {
        int i = (bid - 1024) * 256 + t;
        if (i < 1024) zf[i] = 0.0f;
        return;
    }
    const float* in;
    unsigned short* out;
    int R, C, c0, r0;
    if (bid < 768) {
        in = qkv_w; out = wT1; R = 512; C = 1536;
        c0 = (bid % 48) * 32; r0 = (bid / 48) * 32;
    } else {
        in = out_w; out = wT2; R = 512; C = 512;
        int b2 = bid - 768;
        c0 = (b2 % 16) * 32; r0 = (b2 / 16) * 32;
    }
    int tx = t & 31, ty = t >> 5;
    for (int j = 0; j < 32; j += 8)
        tile[ty + j][tx] = f2b(in[(size_t)(r0 + ty + j) * C + c0 + tx]);
    __syncthreads();
    for (int j = 0; j < 32; j += 8)
        out[(size_t)(c0 + ty + j) * R + r0 + tx] = tile[tx][ty + j];
}

// ---------------- LN1: fp32 x -> bf16 normed; wave-per-row, no LDS ----------------
__global__ __launch_bounds__(256) void ln_apply(const float* __restrict__ x,
                                                const float* __restrict__ g,
                                                const float* __restrict__ bt,
                                                unsigned short* __restrict__ out) {
    int t = threadIdx.x;
    int lane = t & 63, wave = t >> 6;
    size_t row = (size_t)blockIdx.x * 4 + wave;
    const float* p = x + row * 512 + lane * 8;
    float4 va = *(const float4*)p;
    float4 vb = *(const float4*)(p + 4);
    float s = va.x + va.y + va.z + va.w + vb.x + vb.y + vb.z + vb.w;
    float s2 = va.x * va.x + va.y * va.y + va.z * va.z + va.w * va.w +
               vb.x * vb.x + vb.y * vb.y + vb.z * vb.z + vb.w * vb.w;
    for (int o = 32; o > 0; o >>= 1) {
        s += __shfl_xor(s, o);
        s2 += __shfl_xor(s2, o);
    }
    float mean = s * (1.0f / 512.0f);
    float var = s2 * (1.0f / 512.0f) - mean * mean;
    float inv = rsqrtf(var + 1e-5f);
    float4 g0 = *(const float4*)(g + lane * 8);
    float4 g1 = *(const float4*)(g + lane * 8 + 4);
    float4 b0 = *(const float4*)(bt + lane * 8);
    float4 b1 = *(const float4*)(bt + lane * 8 + 4);
    v8s o8;
    o8[0] = (short)f2b((va.x - mean) * inv * g0.x + b0.x);
    o8[1] = (short)f2b((va.y - mean) * inv * g0.y + b0.y);
    o8[2] = (short)f2b((va.z - mean) * inv * g0.z + b0.z);
    o8[3] = (short)f2b((va.w - mean) * inv * g0.w + b0.w);
    o8[4] = (short)f2b((vb.x - mean) * inv * g1.x + b1.x);
    o8[5] = (short)f2b((vb.y - mean) * inv * g1.y + b1.y);
    o8[6] = (short)f2b((vb.z - mean) * inv * g1.z + b1.z);
    o8[7] = (short)f2b((vb.w - mean) * inv * g1.w + b1.w);
    *(v8s*)&out[row * 512 + lane * 8] = o8;
}

// ================================================================================
// gemm8p (gemm1): 256x256 tile, K=512, BK=64 (8 K-tiles), fine-phase schedule.
// 8 waves (2Mx4N), 512 threads, per-wave C = 128x64 = acc[8][4].
// LDS 128KB = 4 rotating regions: region(g) = (dbuf=(g>>1)&1, khalf=g&1), each
// region = A 256x32 (16KB) + B 256x32 (16KB).  Global phase G (16 total) =
// K-slice (kt=G>>1, s=G&1):
//   vmcnt(8) [FIFO: retires CP_G, keeps CP_{G+1},CP_{G+2} in flight]; barrier;
//   stage CP_{G+3} (4 gl_lds -> region (G+3)&3 = region read at G-1, safe);
//   ds_read 12 frags from region G&3; setprio(1); 32 MFMA; setprio(0).
// One barrier per phase, 32 MFMA/barrier.  Regions rotate with period 4 so
// staging never aliases the region being read.  T1 XCD swizzle, T2 both-sides
// granule swizzle, T5 setprio.  Epilogue: full 256x256 C-tile staged in LDS
// (reusing all 128KB), q written row-major coalesced, k/v written transposed
// as kT/vT [bh][d][n].
// ================================================================================
__global__ __launch_bounds__(512) void gemm8p(const unsigned short* __restrict__ A,
                                              const unsigned short* __restrict__ Bt,
                                              const float* __restrict__ bias,
                                              unsigned short* __restrict__ o0,
                                              unsigned short* __restrict__ o1,
                                              unsigned short* __restrict__ o2) {
    __shared__ __align__(16) unsigned short LB[65536];  // 128KB
    int t = threadIdx.x;
    int wave = t >> 6, lane = t & 63;
    int wm = wave >> 2, wn = wave & 3;           // 2 M-halves x 4 N-quarters
    int mrow = lane & 15, kq4 = lane >> 4;
    // XCD-aware bijective chunked swizzle (grid 768 % 8 == 0)
    int cpx = gridDim.x >> 3;
    int bid = blockIdx.x;
    int swz = (bid & 7) * cpx + (bid >> 3);
    int n0 = (swz % 6) * 256;
    int m0 = (swz / 6) * 256;
    const unsigned short* Ab = A + (size_t)m0 * 512;
    const unsigned short* Bb = Bt + (size_t)n0 * 512;
    // staging geometry: unit = 256 rows x 32 K-cols = 1024 granules; thread t
    // covers granules t (rows 0..127) and t+512 (rows 128..255); source
    // col-granule swizzled cs = (t&3) ^ ((t>>2)&3); LDS dest linear.
    int rr0 = t >> 2;
    int cs = ((t & 3) ^ (rr0 & 3)) * 8;
    size_t rowoff0 = (size_t)rr0 * 512 + cs;
    size_t rowoff1 = rowoff0 + (size_t)128 * 512;  // (128+rr0)&3 == rr0&3
    unsigned woff = wave * 512;                     // wave-uniform dest (shorts)
    v4f acc[8][4] = {};
    int swr = ((kq4 ^ (mrow & 3)) << 3);

#define STAGE_CP(g)                                                        \
    do {                                                                   \
        const unsigned short* As_ = Ab + ((g) >> 1) * 64 + ((g) & 1) * 32; \
        const unsigned short* Bs_ = Bb + ((g) >> 1) * 64 + ((g) & 1) * 32; \
        unsigned rg = ((((g) >> 1) & 1) << 15) + (((g) & 1) << 13);        \
        gl_lds16(As_ + rowoff0, &LB[rg + woff]);                           \
        gl_lds16(As_ + rowoff1, &LB[rg + 4096 + woff]);                    \
        gl_lds16(Bs_ + rowoff0, &LB[rg + 16384 + woff]);                   \
        gl_lds16(Bs_ + rowoff1, &LB[rg + 16384 + 4096 + woff]);            \
    } while (0)

    STAGE_CP(0);
    STAGE_CP(1);
    STAGE_CP(2);
#pragma unroll
    for (int G = 0; G < 16; ++G) {
        if (G <= 13) {
            asm volatile("s_waitcnt vmcnt(8)" ::: "memory");
        } else if (G == 14) {
            asm volatile("s_waitcnt vmcnt(4)" ::: "memory");
        } else {
            asm volatile("s_waitcnt vmcnt(0)" ::: "memory");
        }
        __builtin_amdgcn_s_barrier();
        asm volatile("" ::: "memory");
        if (G + 3 < 16) STAGE_CP(G + 3);
        unsigned base = (((G >> 1) & 1) << 15) + ((G & 1) << 13);
        const unsigned short* as = &LB[base];
        const unsigned short* bs = &LB[base + 16384];
        v8s af[8], bf[4];
#pragma unroll
        for (int i = 0; i < 8; i++)
            af[i] = *(const v8s*)&as[(wm * 128 + i * 16 + mrow) * 32 + swr];
#pragma unroll
        for (int j = 0; j < 4; j++)
            bf[j] = *(const v8s*)&bs[(wn * 64 + j * 16 + mrow) * 32 + swr];
        __builtin_amdgcn_s_setprio(1);
#pragma unroll
        for (int i = 0; i < 8; i++)
#pragma unroll
            for (int j = 0; j < 4; j++)
                acc[i][j] = __builtin_amdgcn_mfma_f32_16x16x32_bf16(af[i], bf[j], acc[i][j], 0, 0, 0);
        __builtin_amdgcn_s_setprio(0);
    }
#undef STAGE_CP
    // ---------------- epilogue: full 256x256 C tile in LDS (stride 256, swizzled) ----
    __syncthreads();
    bool doRelu = (n0 < 1024);
#pragma unroll
    for (int j = 0; j < 4; j++) {
        int col = wn * 64 + j * 16 + mrow;          // tile-local col 0..255
        float bv = bias[n0 + col];
        int gr = col >> 3, gb = col & 7;
#pragma unroll
        for (int i = 0; i < 8; i++) {
            int rowb = wm * 128 + i * 16 + kq4 * 4;
#pragma unroll
            for (int r = 0; r < 4; r++) {
                int row = rowb + r;
                float v = acc[i][j][r] + bv;
                if (doRelu) v = fmaxf(v, 0.0f);
                LB[row * 256 + ((gr ^ swz8(row)) << 3) + gb] = f2b(v);
            }
        }
    }
    __syncthreads();
    if (n0 < 512) {
        // q: coalesced row-major
#pragma unroll
        for (int p = 0; p < 16; p++) {
            int g = p * 512 + t;
            int row = g >> 5, gl = g & 31;
            v8s v = *(const v8s*)&LB[row * 256 + ((gl ^ swz8(row)) << 3)];
            *(v8s*)&o0[(size_t)(m0 + row) * 512 + n0 + gl * 8] = v;
        }
    } else {
        // kT (512<=n0<1024) or vT (>=1024): transposed write, layout [bh][d][n]
        unsigned short* Tb = (n0 < 1024) ? o1 : o2;
        int bb = m0 >> 12, gc = m0 & 4095;
#pragma unroll
        for (int p = 0; p < 16; p++) {
            int chunk = p * 512 + t;
            int c = chunk >> 5, rseg = chunk & 31;
            int cglob = n0 + c;
            int hl = (cglob & 511) >> 6, d = cglob & 63;
            int cg = c >> 3, cb7 = c & 7;
            v8s v;
#pragma unroll
            for (int e = 0; e < 8; e++) {
                int rowi = rseg * 8 + e;
                v[e] = (short)LB[rowi * 256 + ((cg ^ swz8(rowi)) << 3) + cb7];
            }
            *(v8s*)&Tb[((size_t)((bb * 8 + hl) * 64 + d)) * 4096 + gc + rseg * 8] = v;
        }
    }
}

// ================================================================================
// gemm2: 256x128-tile, K=512 (16 K-tiles of BK=32), 8 waves (4Mx2N), r4-proven
// 3-slot ring + counted vmcnt(3) structure (2 blocks/CU).
// ================================================================================
__global__ __launch_bounds__(512, 4) void gemm2k(const unsigned short* __restrict__ A,
                                                 const unsigned short* __restrict__ Bt,
                                                 const float* __restrict__ bias,
                                                 unsigned short* __restrict__ o0) {
    __shared__ __align__(16) unsigned short LB[3][12288];
    int t = threadIdx.x;
    int wave = t >> 6, lane = t & 63;
    int wm = wave >> 1, wn = wave & 1;
    int mrow = lane & 15, kq4 = lane >> 4;
    int cpx = gridDim.x >> 3;
    int bid = blockIdx.x;
    int swz = (bid & 7) * cpx + (bid >> 3);
    int n0 = (swz % 4) * 128;
    int m0 = (swz / 4) * 256;
    const unsigned short* Ab = A + (size_t)m0 * 512;
    const unsigned short* Bb = Bt + (size_t)n0 * 512;
    int rA0 = t >> 2;
    int cA0 = (((t & 3) ^ ((rA0 >> 1) & 3)) * 8);
    int rA1 = 128 + (t >> 2);
    int cA1 = (((t & 3) ^ ((rA1 >> 1) & 3)) * 8);
    size_t srcA0 = (size_t)rA0 * 512 + cA0;
    size_t srcA1 = (size_t)rA1 * 512 + cA1;
    unsigned offA0 = wave * 512;
    unsigned offA1 = 4096 + wave * 512;
    unsigned offB  = 8192 + wave * 512;
    v4f acc[4][4] = {};
    int swr = ((kq4 ^ ((mrow >> 1) & 3)) * 8);

#define STAGE(kt, slot)                                          \
    do {                                                         \
        const unsigned short* aS = Ab + (size_t)(kt) * 32;       \
        const unsigned short* bS = Bb + (size_t)(kt) * 32;       \
        gl_lds16(aS + srcA0, &LB[slot][offA0]);                  \
        gl_lds16(aS + srcA1, &LB[slot][offA1]);                  \
        gl_lds16(bS + srcA0, &LB[slot][offB]);                   \
    } while (0)

    STAGE(0, 0);
    STAGE(1, 1);
    for (int kt = 0; kt < 16; ++kt) {
        if (kt < 15) {
            asm volatile("s_waitcnt vmcnt(3)" ::: "memory");
        } else {
            asm volatile("s_waitcnt vmcnt(0)" ::: "memory");
        }
        __builtin_amdgcn_s_barrier();
        asm volatile("" ::: "memory");
        if (kt + 2 < 16) STAGE(kt + 2, (kt + 2) % 3);
        const unsigned short* as = LB[kt % 3];
        const unsigned short* bs = LB[kt % 3] + 8192;
        v8s af[4], bf[4];
#pragma unroll
        for (int i = 0; i < 4; i++)
            af[i] = *(const v8s*)&as[(wm * 64 + i * 16 + mrow) * 32 + swr];
#pragma unroll
        for (int j = 0; j < 4; j++)
            bf[j] = *(const v8s*)&bs[(wn * 64 + j * 16 + mrow) * 32 + swr];
        __builtin_amdgcn_s_setprio(1);
#pragma unroll
        for (int i = 0; i < 4; i++)
#pragma unroll
            for (int j = 0; j < 4; j++)
                acc[i][j] = __builtin_amdgcn_mfma_f32_16x16x32_bf16(af[i], bf[j], acc[i][j], 0, 0, 0);
        __builtin_amdgcn_s_setprio(0);
    }
#undef STAGE
    __syncthreads();
    unsigned short* CT = &LB[0][0];
#pragma unroll
    for (int j = 0; j < 4; j++) {
        int col = wn * 64 + j * 16 + mrow;
        float bv = bias[n0 + col];
        int gr = col >> 3, gb = col & 7;
#pragma unroll
        for (int i = 0; i < 4; i++) {
            int rowb = wm * 64 + i * 16 + kq4 * 4;
#pragma unroll
            for (int r = 0; r < 4; r++) {
                int row = rowb + r;
                CT[row * 136 + ((gr ^ swz8(row)) << 3) + gb] = f2b(acc[i][j][r] + bv);
            }
        }
    }
    __syncthreads();
#pragma unroll
    for (int p = 0; p < 8; p++) {
        int g = p * 512 + t;
        int row = g >> 4, gl = g & 15;
        v8s v = *(const v8s*)&CT[row * 136 + ((gl ^ swz8(row)) << 3)];
        *(v8s*)&o0[(size_t)(m0 + row) * 512 + n0 + gl * 8] = v;
    }
}

// ---------------- kv partials via MFMA: KV[dk][dv] = sum_n kT[dk][n]*vT[dv][n] --------
__global__ __launch_bounds__(256) void kv_part(const unsigned short* __restrict__ kT,
                                               const unsigned short* __restrict__ vT,
                                               float* __restrict__ kvp,
                                               float* __restrict__ ksp) {
    __shared__ __align__(16) unsigned short LB[3][4096];
    int bh = blockIdx.x, nc = blockIdx.y;
    int t = threadIdx.x;
    int w = t >> 6, lane = t & 63;
    int wdk = w >> 1, wdv = w & 1;
    int mrow = lane & 15, kq4 = lane >> 4;
    const unsigned short* Kb = kT + (size_t)bh * 262144 + nc * 512;
    const unsigned short* Vb = vT + (size_t)bh * 262144 + nc * 512;
    int rA = t >> 2;
    int lcA = (t & 3) ^ (rA & 3);
    size_t srcoff = (size_t)rA * 4096 + lcA * 8;
    unsigned dstK = w * 512;
    unsigned dstV = 2048 + w * 512;
    v4f acc[2][2] = {};
    v4f accs[2] = {};
    v8s ones;
#pragma unroll
    for (int jj = 0; jj < 8; jj++) ones[jj] = (short)0x3F80;

#define KSTAGE(ks, slot)                                            \
    do {                                                            \
        gl_lds16(Kb + (size_t)(ks) * 32 + srcoff, &LB[slot][dstK]); \
        gl_lds16(Vb + (size_t)(ks) * 32 + srcoff, &LB[slot][dstV]); \
    } while (0)

    KSTAGE(0, 0);
    KSTAGE(1, 1);
    for (int ks = 0; ks < 16; ++ks) {
        if (ks < 15) {
            asm volatile("s_waitcnt vmcnt(2)" ::: "memory");
        } else {
            asm volatile("s_waitcnt vmcnt(0)" ::: "memory");
        }
        __builtin_amdgcn_s_barrier();
        asm volatile("" ::: "memory");
        if (ks + 2 < 16) KSTAGE(ks + 2, (ks + 2) % 3);
        const unsigned short* as = LB[ks % 3];
        v8s af[2], bf[2];
#pragma unroll
        for (int i = 0; i < 2; i++) {
            int row = wdk * 32 + i * 16 + mrow;
            af[i] = *(const v8s*)&as[row * 32 + ((kq4 ^ (row & 3)) << 3)];
        }
#pragma unroll
        for (int j = 0; j < 2; j++) {
            int row = wdv * 32 + j * 16 + mrow;
            bf[j] = *(const v8s*)&as[2048 + row * 32 + ((kq4 ^ (row & 3)) << 3)];
        }
#pragma unroll
        for (int i = 0; i < 2; i++)
#pragma unroll
            for (int j = 0; j < 2; j++)
                acc[i][j] = __builtin_amdgcn_mfma_f32_16x16x32_bf16(af[i], bf[j], acc[i][j], 0, 0, 0);
        if (wdv == 0) {
#pragma unroll
            for (int i = 0; i < 2; i++)
                accs[i] = __builtin_amdgcn_mfma_f32_16x16x32_bf16(af[i], ones, accs[i], 0, 0, 0);
        }
    }
#undef KSTAGE
    float* dst = kvp + ((size_t)(bh * 8 + nc)) * 4096;
#pragma unroll
    for (int i = 0; i < 2; i++)
#pragma unroll
        for (int j = 0; j < 2; j++)
#pragma unroll
            for (int r = 0; r < 4; r++) {
                int row = wdk * 32 + i * 16 + kq4 * 4 + r;
                int col = wdv * 32 + j * 16 + mrow;
                dst[row * 64 + col] = acc[i][j][r];
            }
    if (wdv == 0 && mrow == 0) {
        float* kd = ksp + ((size_t)(bh * 8 + nc)) * 64 + wdk * 32;
#pragma unroll
        for (int i = 0; i < 2; i++)
#pragma unroll
            for (int r = 0; r < 4; r++)
                kd[i * 16 + kq4 * 4 + r] = accs[i][r];
    }
}

// ---------------- kv reduce: sum 8 partials -> bf16 hi/lo planes + nrm planes --------
__global__ __launch_bounds__(256) void kv_reduce(const float* __restrict__ kvp,
                                                 const float* __restrict__ ksp,
                                                 unsigned short* __restrict__ kvhT,
                                                 unsigned short* __restrict__ kvlT,
                                                 unsigned short* __restrict__ nrmp) {
    int tid = blockIdx.x * 256 + threadIdx.x;
    int bh = tid >> 12, e = tid & 4095;
    int dk = e >> 6, dv = e & 63;
    float s = 0.0f;
#pragma unroll
    for (int c = 0; c < 8; c++) s += kvp[((size_t)(bh * 8 + c)) * 4096 + e];
    unsigned short hb = f2b(s);
    kvhT[(size_t)bh * 4096 + dv * 64 + dk] = hb;
    kvlT[(size_t)bh * 4096 + dv * 64 + dk] = f2b(s - b2f(hb));
    if (tid < 4096) {
        int bh2 = tid >> 6, dk2 = tid & 63;
        float x = 0.0f;
#pragma unroll
        for (int c = 0; c < 8; c++) x += ksp[(bh2 * 8 + c) * 64 + dk2];
        x = fmaxf(x, 100.0f);
        unsigned short nh = f2b(x);
        nrmp[bh2 * 128 + dk2] = nh;
        nrmp[bh2 * 128 + 64 + dk2] = f2b(x - b2f(nh));
    }
}

// ---------------- attn via MFMA; IN-PLACE over q; pre-split bf16 planes -------------
__global__ __launch_bounds__(256) void attn_mfma(unsigned short* __restrict__ qa,
                                                 const unsigned short* __restrict__ kvhT,
                                                 const unsigned short* __restrict__ kvlT,
                                                 const unsigned short* __restrict__ nrmp) {
    __shared__ __align__(16) unsigned short olds[4][4096];
    int bh = blockIdx.y;
    int b = bh >> 3, h = bh & 7;
    int t = threadIdx.x;
    int w = t >> 6, lane = t & 63;
    int mrow = lane & 15, kq4 = lane >> 4;
    int nb = blockIdx.x * 256 + w * 64;
    unsigned short* qbase = qa + ((size_t)(b * 4096 + nb)) * 512 + h * 64;
    v4f acc[4][4] = {};
    v4f accd[4] = {};
#pragma unroll
    for (int s = 0; s < 2; s++) {
        v8s af[4];
#pragma unroll
        for (int i = 0; i < 4; i++)
            af[i] = *(const v8s*)&qbase[(size_t)(i * 16 + mrow) * 512 + s * 32 + kq4 * 8];
        v8s nh = *(const v8s*)&nrmp[bh * 128 + s * 32 + kq4 * 8];
        v8s nl = *(const v8s*)&nrmp[bh * 128 + 64 + s * 32 + kq4 * 8];
#pragma unroll
        for (int i = 0; i < 4; i++) {
            accd[i] = __builtin_amdgcn_mfma_f32_16x16x32_bf16(af[i], nh, accd[i], 0, 0, 0);
            accd[i] = __builtin_amdgcn_mfma_f32_16x16x32_bf16(af[i], nl, accd[i], 0, 0, 0);
        }
#pragma unroll
        for (int j = 0; j < 4; j++) {
            v8s kh = *(const v8s*)&kvhT[(size_t)bh * 4096 + (j * 16 + mrow) * 64 + s * 32 + kq4 * 8];
            v8s kl = *(const v8s*)&kvlT[(size_t)bh * 4096 + (j * 16 + mrow) * 64 + s * 32 + kq4 * 8];
#pragma unroll
            for (int i = 0; i < 4; i++) {
                acc[i][j] = __builtin_amdgcn_mfma_f32_16x16x32_bf16(af[i], kh, acc[i][j], 0, 0, 0);
                acc[i][j] = __builtin_amdgcn_mfma_f32_16x16x32_bf16(af[i], kl, acc[i][j], 0, 0, 0);
            }
        }
    }
    unsigned short* ol = olds[w];
#pragma unroll
    for (int i = 0; i < 4; i++) {
        float inv[4];
#pragma unroll
        for (int r = 0; r < 4; r++) inv[r] = 1.0f / fmaxf(accd[i][r], 100.0f);
#pragma unroll
        for (int j = 0; j < 4; j++) {
            int dv = j * 16 + mrow;
#pragma unroll
            for (int r = 0; r < 4; r++) {
                int rl = i * 16 + kq4 * 4 + r;
                ol[rl * 64 + (((dv >> 3) ^ (rl & 7)) << 3) + (dv & 7)] = f2b(acc[i][j][r] * inv[r]);
            }
        }
    }
    __syncthreads();
#pragma unroll
    for (int p = 0; p < 8; p++) {
        int idx = p * 64 + lane;
        int row = idx >> 3, gl = idx & 7;
        v8s v = *(const v8s*)&ol[row * 64 + ((gl ^ (row & 7)) << 3)];
        *(v8s*)&qbase[(size_t)row * 512 + gl * 8] = v;
    }
}

// ---------------- fused LN2 + transpose: [B,N,C] bf16 -> LN -> [B,C,N] bf16 ----------
__global__ __launch_bounds__(256) void ln2_transpose(const unsigned short* __restrict__ in,
                                                     const float* __restrict__ g,
                                                     const float* __restrict__ bt,
                                                     unsigned short* __restrict__ out) {
    int bid = blockIdx.x;
    int b = bid >> 6;
    int n0 = (bid & 63) * 64;
    __shared__ float gs[512], bs[512];
    __shared__ __align__(16) unsigned short tile[512 * 64];
    int t = threadIdx.x;
    for (int i = t; i < 512; i += 256) { gs[i] = g[i]; bs[i] = bt[i]; }
    int nl = t >> 2, sub = t & 3;
    const unsigned short* src = in + ((size_t)(b * 4096 + n0 + nl)) * 512 + sub * 8;
    v8s vv[16];
#pragma unroll
    for (int c16 = 0; c16 < 16; c16++)
        vv[c16] = *(const v8s*)&src[c16 * 32];
    float s = 0.f, s2 = 0.f;
#pragma unroll
    for (int c16 = 0; c16 < 16; c16++)
#pragma unroll
        for (int j = 0; j < 8; j++) {
            float f = b2f((unsigned short)vv[c16][j]);
            s += f; s2 += f * f;
        }
    s += __shfl_xor(s, 1); s2 += __shfl_xor(s2, 1);
    s += __shfl_xor(s, 2); s2 += __shfl_xor(s2, 2);
    float mean = s * (1.f / 512.f);
    float var = s2 * (1.f / 512.f) - mean * mean;
    float inv = rsqrtf(var + 1e-5f);
    __syncthreads();
#pragma unroll
    for (int c16 = 0; c16 < 16; c16++) {
        int cb_ = sub * 8 + c16 * 32;
#pragma unroll
        for (int j = 0; j < 8; j++) {
            int c = cb_ + j;
            float f = b2f((unsigned short)vv[c16][j]);
            float y = (f - mean) * inv * gs[c] + bs[c];
            tile[c * 64 + ((((nl >> 3) ^ (c & 7)) << 3) | (nl & 7))] = f2b(y);
        }
    }
    __syncthreads();
    unsigned short* dst = out + ((size_t)b * 512) * 4096 + n0;
#pragma unroll
    for (int p = 0; p < 16; p++) {
        int chunk = p * 256 + t;
        int c = chunk >> 3, gseg = chunk & 7;
        int phys = gseg ^ (c & 7);
        v8s v = *(const v8s*)&tile[c * 64 + phys * 8];
        *(v8s*)&dst[(size_t)c * 4096 + gseg * 8] = v;
    }
}

// ---------------- depthwise conv 7x7 + GELU + BN stats; column-sliding ----------
__global__ __launch_bounds__(256) void dwconv7_gelu(const unsigned short* __restrict__ in,
                                                    const float* __restrict__ w,
                                                    const float* __restrict__ bias,
                                                    unsigned short* __restrict__ out,
                                                    float* __restrict__ bn_sum,
                                                    float* __restrict__ bn_sumsq) {
    int bc = blockIdx.x;
    int c = bc & 511;
    __shared__ float img[70 * 72];
    __shared__ float wsm[49];
    __shared__ float r1[4], r2[4];
    int t = threadIdx.x;
    int tx = t & 63, ty = t >> 6;
    for (int i = t; i < 70 * 72; i += 256) img[i] = 0.0f;
    if (t < 49) wsm[t] = w[c * 49 + t];
    __syncthreads();
    const unsigned short* src = in + (size_t)bc * 4096;
#pragma unroll
    for (int q = t; q < 512; q += 256) {
        v8s v = *(const v8s*)&src[q * 8];
        float* ip = &img[((q >> 3) + 3) * 72 + (q & 7) * 8 + 3];
#pragma unroll
        for (int j = 0; j < 8; j++) ip[j] = b2f((unsigned short)v[j]);
    }
    __syncthreads();
    float wt[49];
#pragma unroll
    for (int i = 0; i < 49; i++) wt[i] = wsm[i];
    float bv = bias[c];
    float acc[16];
#pragma unroll
    for (int i = 0; i < 16; i++) acc[i] = bv;
    int h0 = ty * 16;
#pragma unroll
    for (int rr = 0; rr < 22; rr++) {
        float v[7];
#pragma unroll
        for (int kw = 0; kw < 7; kw++) v[kw] = img[(h0 + rr) * 72 + tx + kw];
#pragma unroll
        for (int kh = 0; kh < 7; kh++) {
            int o = rr - kh;
            if (o >= 0 && o <= 15) {
                float dot = v[0] * wt[kh * 7];
#pragma unroll
                for (int kw = 1; kw < 7; kw++) dot += v[kw] * wt[kh * 7 + kw];
                acc[o] += dot;
            }
        }
    }
    float s = 0.0f, s2 = 0.0f;
    unsigned short* dst = out + (size_t)bc * 4096;
#pragma unroll
    for (int i = 0; i < 16; i++) {
        float a = acc[i];
        float ge = 0.5f * a * (1.0f + erff(a * 0.70710678118f));
        dst[(h0 + i) * 64 + tx] = f2b(ge);
        s += ge;
        s2 += ge * ge;
    }
    for (int o = 32; o > 0; o >>= 1) {
        s += __shfl_down(s, o);
        s2 += __shfl_down(s2, o);
    }
    int lane = t & 63;
    if (lane == 0) { r1[ty] = s; r2[ty] = s2; }
    __syncthreads();
    if (t == 0) {
        atomicAdd(&bn_sum[c], r1[0] + r1[1] + r1[2] + r1[3]);
        atomicAdd(&bn_sumsq[c], r2[0] + r2[1] + r2[2] + r2[3]);
    }
}

__global__ void bn_finalize(const float* __restrict__ s, const float* __restrict__ s2,
                            const float* __restrict__ g, const float* __restrict__ b,
                            float2* __restrict__ ab) {
    int c = blockIdx.x * blockDim.x + threadIdx.x;
    if (c >= 512) return;
    float m = s[c] * (1.0f / 32768.0f);
    float var = s2[c] * (1.0f / 32768.0f) - m * m;
    float inv = rsqrtf(var + 1e-5f);
    float sc = g[c] * inv;
    ab[c] = make_float2(sc, b[c] - m * sc);
}

// ---------------- depthwise conv 7x7 with BN affine on load; column-sliding -------------------
__global__ __launch_bounds__(256) void dwconv7_bn(const unsigned short* __restrict__ in,
                                                  const float2* __restrict__ bnab,
                                                  const float* __restrict__ w,
                                                  const float* __restrict__ bias,
                                                  unsigned short* __restrict__ out) {
    int bc = blockIdx.x;
    int c = bc & 511;
    __shared__ float img[70 * 72];
    __shared__ float wsm[49];
    int t = threadIdx.x;
    int tx = t & 63, ty = t >> 6;
    for (int i = t; i < 70 * 72; i += 256) img[i] = 0.0f;
    if (t < 49) wsm[t] = w[c * 49 + t];
    __syncthreads();
    float2 ab = bnab[c];
    const unsigned short* src = in + (size_t)bc * 4096;
#pragma unroll
    for (int q = t; q < 512; q += 256) {
        v8s v = *(const v8s*)&src[q * 8];
        float* ip = &img[((q >> 3) + 3) * 72 + (q & 7) * 8 + 3];
#pragma unroll
        for (int j = 0; j < 8; j++) ip[j] = b2f((unsigned short)v[j]) * ab.x + ab.y;
    }
    __syncthreads();
    float wt[49];
#pragma unroll
    for (int i = 0; i < 49; i++) wt[i] = wsm[i];
    float bv = bias[c];
    float acc[16];
#pragma unroll
    for (int i = 0; i < 16; i++) acc[i] = bv;
    int h0 = ty * 16;
#pragma unroll
    for (int rr = 0; rr < 22; rr++) {
        float v[7];
#pragma unroll
        for (int kw = 0; kw < 7; kw++) v[kw] = img[(h0 + rr) * 72 + tx + kw];
#pragma unroll
        for (int kh = 0; kh < 7; kh++) {
            int o = rr - kh;
            if (o >= 0 && o <= 15) {
                float dot = v[0] * wt[kh * 7];
#pragma unroll
                for (int kw = 1; kw < 7; kw++) dot += v[kw] * wt[kh * 7 + kw];
                acc[o] += dot;
            }
        }
    }
    unsigned short* dst = out + (size_t)bc * 4096;
#pragma unroll
    for (int i = 0; i < 16; i++)
        dst[(h0 + i) * 64 + tx] = f2b(acc[i]);
}

// ---------------- final: out = x(f32) + attn(bf16) + y2^T(bf16) -> f32; 4 tiles/block ---------
__global__ __launch_bounds__(256) void final_add(const float* __restrict__ x,
                                                 const unsigned short* __restrict__ attn,
                                                 const unsigned short* __restrict__ y2,
                                                 float* __restrict__ out) {
    __shared__ unsigned short tile[32][36];
    int b = blockIdx.z;
    int c0 = blockIdx.x * 32;
    int n0b = blockIdx.y * 128;
    int t = threadIdx.x;
#pragma unroll
    for (int nt = 0; nt < 4; ++nt) {
        int n0 = n0b + nt * 32;
        __syncthreads();
        {
            int c = t >> 3, n4 = (t & 7) * 4;
            ushort4 v = *(const ushort4*)&y2[((size_t)(b * 512 + c0 + c)) * 4096 + n0 + n4];
            tile[c][n4] = v.x; tile[c][n4 + 1] = v.y; tile[c][n4 + 2] = v.z; tile[c][n4 + 3] = v.w;
        }
        __syncthreads();
        int nl = t >> 3, cl = (t & 7) * 4;
        size_t idx = ((size_t)(b * 4096 + n0 + nl)) * 512 + c0 + cl;
        float4 xv = *(const float4*)&x[idx];
        ushort4 av = *(const ushort4*)&attn[idx];
        float4 o;
        o.x = xv.x + b2f(av.x) + b2f(tile[cl][nl]);
        o.y = xv.y + b2f(av.y) + b2f(tile[cl + 1][nl]);
        o.z = xv.z + b2f(av.z) + b2f(tile[cl + 2][nl]);
        o.w = xv.w + b2f(av.w) + b2f(tile[cl + 3][nl]);
        *(float4*)&out[idx] = o;
    }
}

// ------------------------------------------------------------------------------------------------
extern "C" void kernel_launch(void* const* d_in, const int* in_sizes, int n_in,
                              void* d_out, int out_size, void* d_ws, size_t ws_size,
                              hipStream_t stream) {
    const float* x     = (const float*)d_in[0];
    const float* qkv_w = (const float*)d_in[1];
    const float* qkv_b = (const float*)d_in[2];
    const float* out_w = (const float*)d_in[3];
    const float* out_b = (const float*)d_in[4];
    const float* pre_g = (const float*)d_in[5];
    const float* pre_b = (const float*)d_in[6];
    const float* lcm_g = (const float*)d_in[7];
    const float* lcm_b = (const float*)d_in[8];
    const float* ci_w  = (const float*)d_in[9];
    const float* ci_b  = (const float*)d_in[10];
    const float* bn_g  = (const float*)d_in[11];
    const float* bn_b  = (const float*)d_in[12];
    const float* co_w  = (const float*)d_in[13];
    const float* co_b  = (const float*)d_in[14];

    char* ws = (char*)d_ws;
    const size_t SLOT = 33554432;  // 32768*512*2 bytes (bf16)
    unsigned short* S0 = (unsigned short*)(ws);               // q -> attn -> xi -> y2
    unsigned short* S1 = (unsigned short*)(ws + SLOT);        // kT -> attn_out(bf16)
    unsigned short* S2 = (unsigned short*)(ws + 2 * SLOT);    // vT -> y
    const size_t MISC = 3 * SLOT;                             // 96MB
    unsigned short* wT1 = (unsigned short*)(ws + MISC);                 // 1.5MB bf16
    unsigned short* wT2 = (unsigned short*)(ws + MISC + 1572864);       // 0.5MB bf16
    float* bn_sum       = (float*)(ws + MISC + 2097152);                // 2KB
    float* bn_sumsq     = (float*)(ws + MISC + 2097152 + 2048);         // 2KB
    float2* bnab        = (float2*)(ws + MISC + 2097152 + 4096);        // 4KB
    float* ksp          = (float*)(ws + MISC + 2105344);                // 128KB
    float* outp         = (float*)d_out;

    // d_out doubles as scratch before final_add fully overwrites it:
    unsigned short* normed = (unsigned short*)d_out;                    // 32MB bf16
    float* kvp             = (float*)((char*)d_out + SLOT);             // 8MB fp32 partials
    unsigned short* kvhT   = (unsigned short*)((char*)d_out + SLOT + 8388608);   // 512KB
    unsigned short* kvlT   = kvhT + 262144;                             // 512KB
    unsigned short* nrmp   = kvlT + 262144;                             // 16KB

    prep<<<1028, 256, 0, stream>>>(qkv_w, out_w, wT1, wT2, bn_sum);
    ln_apply<<<8192, 256, 0, stream>>>(x, pre_g, pre_b, normed);
    // gemm1: M=32768/256=128, N=1536/256=6 -> 768 blocks (%8==0); writes q + kT + vT
    gemm8p<<<768, 512, 0, stream>>>(normed, wT1, qkv_b, S0, S1, S2);
    kv_part<<<dim3(64, 8), 256, 0, stream>>>(S1, S2, kvp, ksp);
    kv_reduce<<<1024, 256, 0, stream>>>(kvp, ksp, kvhT, kvlT, nrmp);
    attn_mfma<<<dim3(16, 64), 256, 0, stream>>>(S0, kvhT, kvlT, nrmp);
    // gemm2: M=128, N=512/128=4 -> 512 blocks (%8==0)
    gemm2k<<<512, 512, 0, stream>>>(S0, wT2, out_b, S1);
    // fused LN2 + transpose: S1 [B,N,C] -> S0 [B,C,N]
    ln2_transpose<<<512, 256, 0, stream>>>(S1, lcm_g, lcm_b, S0);
    dwconv7_gelu<<<4096, 256, 0, stream>>>(S0, ci_w, ci_b, S2, bn_sum, bn_sumsq);
    bn_finalize<<<2, 256, 0, stream>>>(bn_sum, bn_sumsq, bn_g, bn_b, bnab);
    dwconv7_bn<<<4096, 256, 0, stream>>>(S2, bnab, co_w, co_b, S0);
    final_add<<<dim3(16, 32, 8), 256, 0, stream>>>(x, S1, S0, outp);
}